// Round 1
// baseline (112.532 us; speedup 1.0000x reference)
//
#include <hip/hip_runtime.h>
#include <stdint.h>

// DoctoralLoss: total = mean_{T,B}(nll(logits + std*z)) + 0.5*pinball + 0.1*mean(exp(log_var))
// B=131072 rows, C=3 classes, T=100 MC samples, Q=0.5.
// MC term is re-sampled with our own counter-based RNG (triple32 hash + Box-Muller):
// unbiased, deviation from the JAX-eps reference ~6e-4 << 4e-2 threshold.

constexpr int T_SAMPLES = 100;
constexpr int B_ROWS    = 131072;
constexpr int SPLIT     = 4;                 // threads per row
constexpr int TPT       = T_SAMPLES / SPLIT; // 25 samples per thread

__device__ __forceinline__ uint32_t hash32(uint32_t x) {
    // Mueller "triple32" — near-ideal avalanche, bijective
    x ^= x >> 17; x *= 0xed5ad4bbu;
    x ^= x >> 11; x *= 0xac4c1b51u;
    x ^= x >> 15; x *= 0x31848babu;
    x ^= x >> 14;
    return x;
}

__device__ __forceinline__ float u01(uint32_t h) {
    // strictly in (0,1): (m + 0.5) * 2^-23, m in [0, 2^23)
    return ((float)(h >> 9) + 0.5f) * 1.1920928955078125e-7f;
}

__global__ __launch_bounds__(256)
void doctoral_loss_kernel(const float* __restrict__ logits,
                          const float* __restrict__ log_var,
                          const float* __restrict__ p_win,
                          const int*   __restrict__ targets,
                          float*       __restrict__ out)
{
    const int gid = blockIdx.x * blockDim.x + threadIdx.x;
    const int b   = gid >> 2;        // row
    const int q   = gid & 3;         // which quarter of the T loop

    float local = 0.0f;
    if (b < B_ROWS) {
        const float l0 = logits[3 * b + 0];
        const float l1 = logits[3 * b + 1];
        const float l2 = logits[3 * b + 2];
        const float lv = log_var[b];
        const float sd = __expf(0.5f * lv);
        const int   tc = targets[b];

        float acc = 0.0f;
        const uint32_t nbase = (uint32_t)b * (uint32_t)T_SAMPLES + (uint32_t)(q * TPT);
        for (int i = 0; i < TPT; ++i) {
            const uint32_t h = (nbase + (uint32_t)i) * 4u;
            const float u0 = u01(hash32(h + 0u));
            const float u1 = u01(hash32(h + 1u));
            const float u2 = u01(hash32(h + 2u));
            const float u3 = u01(hash32(h + 3u));
            // Box-Muller: 3 normals from 4 uniforms
            const float r0 = sqrtf(-2.0f * __logf(u0));
            const float r1 = sqrtf(-2.0f * __logf(u2));
            const float a0 = 6.283185307179586f * u1;
            const float a1 = 6.283185307179586f * u3;
            const float z0 = r0 * __cosf(a0);
            const float z1 = r0 * __sinf(a0);
            const float z2 = r1 * __cosf(a1);
            // distorted logits
            const float d0 = fmaf(sd, z0, l0);
            const float d1 = fmaf(sd, z1, l1);
            const float d2 = fmaf(sd, z2, l2);
            // stable log-sum-exp over C=3
            const float m   = fmaxf(fmaxf(d0, d1), d2);
            const float s   = __expf(d0 - m) + __expf(d1 - m) + __expf(d2 - m);
            const float lse = m + __logf(s);
            const float dt  = (tc == 0) ? d0 : ((tc == 1) ? d1 : d2);
            acc += lse - dt;   // nll sample
        }
        local = acc * (1.0f / ((float)T_SAMPLES * (float)B_ROWS));

        if (q == 0) {
            // deterministic per-row terms, added once per row
            int pred = 0; float best = l0;
            if (l1 > best) { best = l1; pred = 1; }
            if (l2 > best) { best = l2; pred = 2; }
            const float corr = (pred == tc) ? 1.0f : 0.0f;
            const float err  = corr - p_win[b];
            // 0.5 * pinball(Q=0.5) = 0.25*|err|;  0.1 * exp(log_var)
            local += (0.25f * fabsf(err) + 0.1f * __expf(lv)) * (1.0f / (float)B_ROWS);
        }
    }

    // block reduction: wave64 shuffle, then LDS across the 4 waves
    float v = local;
    #pragma unroll
    for (int off = 32; off > 0; off >>= 1)
        v += __shfl_down(v, off, 64);
    __shared__ float wsum[4];
    const int lane = threadIdx.x & 63;
    const int wid  = threadIdx.x >> 6;
    if (lane == 0) wsum[wid] = v;
    __syncthreads();
    if (threadIdx.x == 0) {
        atomicAdd(out, wsum[0] + wsum[1] + wsum[2] + wsum[3]);
    }
}

__global__ void zero_out_kernel(float* __restrict__ out) {
    if (threadIdx.x == 0 && blockIdx.x == 0) out[0] = 0.0f;
}

extern "C" void kernel_launch(void* const* d_in, const int* in_sizes, int n_in,
                              void* d_out, int out_size, void* d_ws, size_t ws_size,
                              hipStream_t stream) {
    const float* logits   = (const float*)d_in[0];
    const float* log_var  = (const float*)d_in[1];
    const float* p_win    = (const float*)d_in[2];
    const int*   targets  = (const int*)d_in[3];
    float*       out      = (float*)d_out;

    // d_out is poisoned 0xAA before every call — zero it ourselves (graph-safe kernel).
    zero_out_kernel<<<1, 64, 0, stream>>>(out);

    const int total_threads = B_ROWS * SPLIT;           // 524288
    const int block = 256;
    const int grid  = total_threads / block;            // 2048
    doctoral_loss_kernel<<<grid, block, 0, stream>>>(logits, log_var, p_win, targets, out);
}

// Round 2
// 88.692 us; speedup vs baseline: 1.2688x; 1.2688x over previous
//
#include <hip/hip_runtime.h>
#include <stdint.h>

// DoctoralLoss: total = mean_{T,B}(nll(logits + std*z)) + 0.5*pinball + 0.1*mean(exp(log_var))
// B=131072 rows, C=3 classes, T=100 MC samples, Q=0.5.
//
// Key reformulation: nll = log(1 + e^u + e^v), (u,v) = non-target logit diffs vs target.
// (u,v) is exactly N(mu, s^2*[[2,1],[1,2]]) -> sample with 2 normals (one Box-Muller
// pair = one 32-bit rng word). Everything in log2 domain; constants folded per-row:
//   K1 = log2e*sqrt(2ln2)*sqrt(2)*s,  K2 = K1/2,  K3 = log2e*sqrt(2ln2)*sqrt(1.5)*s
//   u~ = mu_u*log2e + K1*r*cos,  v~ = mu_v*log2e + K2*r*cos + K3*r*sin,  r = sqrt(-log2(U))
//   nll = ln2 * log2(1 + 2^u~ + 2^v~)
// RNG: xorshift128 in-loop (bit ops only, no int mul), seeded per-thread by triple32(gid).

constexpr int T_SAMPLES = 100;
constexpr int B_ROWS    = 131072;
constexpr int SPLIT     = 4;                 // threads per row
constexpr int TPT       = T_SAMPLES / SPLIT; // 25 samples per thread

__device__ __forceinline__ uint32_t hash32(uint32_t x) {
    x ^= x >> 17; x *= 0xed5ad4bbu;
    x ^= x >> 11; x *= 0xac4c1b51u;
    x ^= x >> 15; x *= 0x31848babu;
    x ^= x >> 14;
    return x;
}

__global__ __launch_bounds__(256)
void doctoral_loss_kernel(const float* __restrict__ logits,
                          const float* __restrict__ log_var,
                          const float* __restrict__ p_win,
                          const int*   __restrict__ targets,
                          float*       __restrict__ out)
{
    const int gid = blockIdx.x * blockDim.x + threadIdx.x;
    const int b   = gid >> 2;        // row
    const int q   = gid & 3;         // quarter of the T loop

    float local = 0.0f;
    {
        const float l0 = logits[3 * b + 0];
        const float l1 = logits[3 * b + 1];
        const float l2 = logits[3 * b + 2];
        const float lv = log_var[b];
        const int   tc = targets[b];

        // s = exp(0.5*lv) via exp2
        const float s  = __builtin_amdgcn_exp2f(0.72134752f * lv);

        // select target / non-target logits
        const float lt = (tc == 0) ? l0 : ((tc == 1) ? l1 : l2);
        const float la = (tc == 0) ? l1 : l0;
        const float lb = (tc == 2) ? l1 : l2;

        const float LOG2E = 1.4426950408889634f;
        const float mu_u = LOG2E * (la - lt);
        const float mu_v = LOG2E * (lb - lt);
        // log2e*sqrt(2 ln2)*sqrt(2) = 2.4022650; *sqrt(1.5)/sqrt(2) ratio -> 2.0804954
        const float K1 = 2.4022650f * s;
        const float K2 = 0.5f * K1;
        const float K3 = 2.0804954f * s;

        // xorshift128 state, seeded per-thread (bijective hash => never all-zero)
        uint32_t sx = hash32((uint32_t)gid * 4u + 1u);
        uint32_t sy = hash32((uint32_t)gid * 4u + 2u);
        uint32_t sz = hash32((uint32_t)gid * 4u + 3u);
        uint32_t sw = hash32((uint32_t)gid * 4u + 4u);

        float acc = 0.0f;   // sum of log2-nll
        #pragma unroll
        for (int i = 0; i < TPT; ++i) {
            // xorshift128 step
            const uint32_t t = sx ^ (sx << 11);
            sx = sy; sy = sz; sz = sw;
            sw = sw ^ (sw >> 19) ^ t ^ (t >> 8);
            const uint32_t rnd = sw;

            // angle in revolutions [0,1): v_sin/v_cos take revolutions directly
            const float arev = (float)(rnd & 0xffffu) * 1.52587890625e-5f; // 2^-16
            // radius uniform in (0,1): ((rnd>>16)+0.5) * 2^-16
            const float ur = fmaf((float)(rnd >> 16), 1.52587890625e-5f, 7.62939453125e-6f);

            const float nlog = -__builtin_amdgcn_logf(ur);      // -log2(U) in (0,17]
            const float r    = __builtin_amdgcn_sqrtf(nlog);
            const float cs   = __builtin_amdgcn_cosf(arev);
            const float sn   = __builtin_amdgcn_sinf(arev);
            const float rc   = r * cs;
            const float rs   = r * sn;

            float ut = fmaf(K1, rc, mu_u);
            float vt = fmaf(K3, rs, fmaf(K2, rc, mu_v));
            ut = fminf(ut, 120.0f);   // overflow guard, statistically nil
            vt = fminf(vt, 120.0f);

            const float S = 1.0f + __builtin_amdgcn_exp2f(ut) + __builtin_amdgcn_exp2f(vt);
            acc += __builtin_amdgcn_logf(S);   // log2(S) = nll/ln2
        }
        const float LN2 = 0.6931471805599453f;
        local = acc * (LN2 / ((float)T_SAMPLES * (float)B_ROWS));

        if (q == 0) {
            // deterministic per-row terms, added once per row
            int pred = 0; float best = l0;
            if (l1 > best) { best = l1; pred = 1; }
            if (l2 > best) { best = l2; pred = 2; }
            const float corr = (pred == tc) ? 1.0f : 0.0f;
            const float err  = corr - p_win[b];
            // 0.5 * pinball(Q=0.5) = 0.25*|err|;  0.1 * exp(log_var)
            const float elv = __builtin_amdgcn_exp2f(1.4426950408889634f * lv);
            local += (0.25f * fabsf(err) + 0.1f * elv) * (1.0f / (float)B_ROWS);
        }
    }

    // block reduction: wave64 shuffle, then LDS across the 4 waves
    float v = local;
    #pragma unroll
    for (int off = 32; off > 0; off >>= 1)
        v += __shfl_down(v, off, 64);
    __shared__ float wsum[4];
    const int lane = threadIdx.x & 63;
    const int wid  = threadIdx.x >> 6;
    if (lane == 0) wsum[wid] = v;
    __syncthreads();
    if (threadIdx.x == 0) {
        atomicAdd(out, wsum[0] + wsum[1] + wsum[2] + wsum[3]);
    }
}

__global__ void zero_out_kernel(float* __restrict__ out) {
    if (threadIdx.x == 0 && blockIdx.x == 0) out[0] = 0.0f;
}

extern "C" void kernel_launch(void* const* d_in, const int* in_sizes, int n_in,
                              void* d_out, int out_size, void* d_ws, size_t ws_size,
                              hipStream_t stream) {
    const float* logits   = (const float*)d_in[0];
    const float* log_var  = (const float*)d_in[1];
    const float* p_win    = (const float*)d_in[2];
    const int*   targets  = (const int*)d_in[3];
    float*       out      = (float*)d_out;

    zero_out_kernel<<<1, 64, 0, stream>>>(out);

    const int total_threads = B_ROWS * SPLIT;           // 524288
    const int block = 256;
    const int grid  = total_threads / block;            // 2048
    doctoral_loss_kernel<<<grid, block, 0, stream>>>(logits, log_var, p_win, targets, out);
}

// Round 3
// 88.147 us; speedup vs baseline: 1.2766x; 1.0062x over previous
//
#include <hip/hip_runtime.h>
#include <stdint.h>

// DoctoralLoss: total = mean_{T,B}(nll(logits + std*z)) + 0.5*pinball + 0.1*mean(exp(log_var))
// B=131072 rows, C=3 classes, T=100 MC samples, Q=0.5.
//
// nll = log(1 + e^u + e^v), (u,v) = non-target logit diffs vs target, exactly
// N(mu, s^2*[[2,1],[1,2]]). Sampled with 2 normals via Box-Muller in polar form:
//   z0 = R*cos(th), z1 = R*sin(th)
// where (this round's changes):
//   - cos/sin come from a golden-angle ROTATION RECURRENCE (4 fma, no v_sin/v_cos);
//     marginal angle exactly uniform, cross-sample correlation is QMC-like (variance down).
//   - R comes from a 1025-entry LDS inverse-CDF table R(v)=sqrt(-2 ln v), 10-bit index
//     + 6-bit lerp (no v_log/v_sqrt in the loop). Tail capped at 4.86 sigma (bias ~1e-3).
//   - one xorshift128 word feeds TWO samples (16 bits each).
// Remaining trans ops per sample: exp2, exp2, log2 (the LSE itself).

constexpr int T_SAMPLES = 100;
constexpr int B_ROWS    = 131072;
constexpr int SPLIT     = 4;                 // threads per row
constexpr int TPT       = T_SAMPLES / SPLIT; // 25 samples per thread

__device__ __forceinline__ uint32_t hash32(uint32_t x) {
    x ^= x >> 17; x *= 0xed5ad4bbu;
    x ^= x >> 11; x *= 0xac4c1b51u;
    x ^= x >> 15; x *= 0x31848babu;
    x ^= x >> 14;
    return x;
}

__global__ __launch_bounds__(256)
void doctoral_loss_kernel(const float* __restrict__ logits,
                          const float* __restrict__ log_var,
                          const float* __restrict__ p_win,
                          const int*   __restrict__ targets,
                          float*       __restrict__ out)
{
    // --- chi(2-dof) inverse-CDF table: rtab[j] = sqrt(-2 ln(j/1024)), once per block ---
    __shared__ float rtab[1025];
    for (int j = threadIdx.x; j < 1025; j += 256) {
        const float v = (j == 0) ? 7.62939453125e-06f : (float)j * 0.0009765625f; // 1/1024
        rtab[j] = sqrtf(-2.0f * logf(v));
    }
    __syncthreads();

    const int gid = blockIdx.x * blockDim.x + threadIdx.x;
    const int b   = gid >> 2;        // row
    const int q   = gid & 3;         // quarter of the T loop

    float local = 0.0f;
    {
        const float l0 = logits[3 * b + 0];
        const float l1 = logits[3 * b + 1];
        const float l2 = logits[3 * b + 2];
        const float lv = log_var[b];
        const int   tc = targets[b];

        // s = exp(0.5*lv)
        const float s = __builtin_amdgcn_exp2f(0.72134752f * lv);

        const float lt = (tc == 0) ? l0 : ((tc == 1) ? l1 : l2);
        const float la = (tc == 0) ? l1 : l0;
        const float lb = (tc == 2) ? l1 : l2;

        const float LOG2E = 1.4426950408889634f;
        const float mu_u = LOG2E * (la - lt);
        const float mu_v = LOG2E * (lb - lt);
        // Cholesky of [[2,1],[1,2]] scaled: u = mu + s*sqrt2*z0, v = mu + s*(z0/sqrt2 + sqrt(1.5)*z1)
        const float K1 = 2.0404103f * s;   // log2e * sqrt(2)   * s
        const float K2 = 1.0202051f * s;   // log2e / sqrt(2)   * s
        const float K3 = 1.7668165f * s;   // log2e * sqrt(1.5) * s

        // xorshift128 state (bijective hash seeds => never all-zero)
        uint32_t sx = hash32((uint32_t)gid * 8u + 1u);
        uint32_t sy = hash32((uint32_t)gid * 8u + 2u);
        uint32_t sz = hash32((uint32_t)gid * 8u + 3u);
        uint32_t sw = hash32((uint32_t)gid * 8u + 4u);

        // initial angle (revolutions) + golden-angle rotation constants
        const float th0 = (float)hash32((uint32_t)gid * 8u + 5u) * 2.3283064365386963e-10f;
        float c  = __builtin_amdgcn_cosf(th0);   // v_cos takes revolutions
        float sn = __builtin_amdgcn_sinf(th0);
        const float CD = -0.7373688f;  // cos(2*pi*0.618034)
        const float SD = -0.6754903f;  // sin(2*pi*0.618034)

        float acc = 0.0f;   // sum of log2-nll

        auto sample = [&](uint32_t w) {
            // rotate direction by golden angle (exactly uniform marginal)
            const float cn  = fmaf(c,  CD, -(sn * SD));
            const float snn = fmaf(sn, CD,  (c  * SD));
            c = cn; sn = snn;
            // radius via table + lerp: v = (w+0.5)/65536, idx = top 10 bits
            const uint32_t idx = w >> 6;
            const float t0 = rtab[idx];
            const float t1 = rtab[idx + 1];
            const float frac = fmaf((float)(w & 63u), 0.015625f, 0.0078125f);
            const float R  = fmaf(frac, t1 - t0, t0);
            const float rc = R * c;
            const float rs = R * sn;
            float ut = fmaf(K1, rc, mu_u);
            float vt = fmaf(K3, rs, fmaf(K2, rc, mu_v));
            ut = fminf(ut, 125.0f);   // overflow guard (exp2(128)=inf would poison sum)
            vt = fminf(vt, 125.0f);
            const float S = 1.0f + __builtin_amdgcn_exp2f(ut) + __builtin_amdgcn_exp2f(vt);
            acc += __builtin_amdgcn_logf(S);   // log2(S)
        };

        #pragma unroll
        for (int i = 0; i < TPT / 2; ++i) {   // 12 double-iterations
            const uint32_t t = sx ^ (sx << 11);
            sx = sy; sy = sz; sz = sw;
            sw = sw ^ (sw >> 19) ^ t ^ (t >> 8);
            sample(sw & 0xffffu);
            sample(sw >> 16);
        }
        {   // 25th sample
            const uint32_t t = sx ^ (sx << 11);
            sx = sy; sy = sz; sz = sw;
            sw = sw ^ (sw >> 19) ^ t ^ (t >> 8);
            sample(sw & 0xffffu);
        }

        const float LN2 = 0.6931471805599453f;
        local = acc * (LN2 / ((float)T_SAMPLES * (float)B_ROWS));

        if (q == 0) {
            int pred = 0; float best = l0;
            if (l1 > best) { best = l1; pred = 1; }
            if (l2 > best) { best = l2; pred = 2; }
            const float corr = (pred == tc) ? 1.0f : 0.0f;
            const float err  = corr - p_win[b];
            const float elv  = __builtin_amdgcn_exp2f(1.4426950408889634f * lv);
            local += (0.25f * fabsf(err) + 0.1f * elv) * (1.0f / (float)B_ROWS);
        }
    }

    // block reduction: wave64 shuffle, then LDS across the 4 waves
    float v = local;
    #pragma unroll
    for (int off = 32; off > 0; off >>= 1)
        v += __shfl_down(v, off, 64);
    __shared__ float wsum[4];
    const int lane = threadIdx.x & 63;
    const int wid  = threadIdx.x >> 6;
    if (lane == 0) wsum[wid] = v;
    __syncthreads();
    if (threadIdx.x == 0) {
        atomicAdd(out, wsum[0] + wsum[1] + wsum[2] + wsum[3]);
    }
}

__global__ void zero_out_kernel(float* __restrict__ out) {
    if (threadIdx.x == 0 && blockIdx.x == 0) out[0] = 0.0f;
}

extern "C" void kernel_launch(void* const* d_in, const int* in_sizes, int n_in,
                              void* d_out, int out_size, void* d_ws, size_t ws_size,
                              hipStream_t stream) {
    const float* logits   = (const float*)d_in[0];
    const float* log_var  = (const float*)d_in[1];
    const float* p_win    = (const float*)d_in[2];
    const int*   targets  = (const int*)d_in[3];
    float*       out      = (float*)d_out;

    zero_out_kernel<<<1, 64, 0, stream>>>(out);

    const int total_threads = B_ROWS * SPLIT;           // 524288
    const int block = 256;
    const int grid  = total_threads / block;            // 2048
    doctoral_loss_kernel<<<grid, block, 0, stream>>>(logits, log_var, p_win, targets, out);
}